// Round 10
// baseline (357.296 us; speedup 1.0000x reference)
//
#include <hip/hip_runtime.h>
#include <hip/hip_cooperative_groups.h>
#include <stdint.h>

namespace cg = cooperative_groups;

// Problem constants: B=4, T=2048, C=1024, H=16, d=64, R=8. Inputs/outputs fp32.
#define T_LEN 2048
#define C_DIM 1024
#define NHEAD 16
#define DHEAD 64
#define QOFF  8388608L   // float-elem offset of q section in d_out
#define KOFF  16777216L  // float-elem offset of k section in d_out
#define SCALE_LOG2 0.18033688011112042f  // 0.125 * log2(e)

typedef float f32x4 __attribute__((ext_vector_type(4)));
typedef short bf16x8 __attribute__((ext_vector_type(8)));
typedef short s16x4 __attribute__((ext_vector_type(4)));
typedef unsigned short u16;

__device__ __forceinline__ u16 f2b(float f) {
  union { float f; uint32_t u; } v; v.f = f;
  uint32_t r = v.u + 0x7fffu + ((v.u >> 16) & 1u);  // RNE
  return (u16)(r >> 16);
}
__device__ __forceinline__ u16 f2b_tr(float f) {  // truncation: 1 VALU op
  union { float f; uint32_t u; } v; v.f = f;
  return (u16)(v.u >> 16);
}
__device__ __forceinline__ void async16(const u16* g, u16* l) {
  __builtin_amdgcn_global_load_lds((const __attribute__((address_space(1))) void*)g,
                                   (__attribute__((address_space(3))) void*)l, 16, 0, 0);
}

#define MFMA16 __builtin_amdgcn_mfma_f32_16x16x32_bf16

// ---- prep unit (proven prep_all math) --------------------------------------
__device__ __forceinline__ void prep_unit(int b, const float* __restrict__ x,
                                          u16* __restrict__ xc,
                                          const float* __restrict__ w1,
                                          const float* __restrict__ B1,
                                          const float* __restrict__ A1,
                                          u16* __restrict__ w1e,
                                          const float* __restrict__ w2,
                                          const float* __restrict__ B2,
                                          const float* __restrict__ A2,
                                          u16* __restrict__ w2e) {
  if (b < 8192) {
    long i = ((long)b * 256 + threadIdx.x) * 4;
    f32x4 v = *(const f32x4*)(x + i);
    s16x4 r;
    r[0] = (short)f2b(v[0]); r[1] = (short)f2b(v[1]);
    r[2] = (short)f2b(v[2]); r[3] = (short)f2b(v[3]);
    *(s16x4*)(xc + i) = r;
  } else if (b < 20480) {
    int i = (b - 8192) * 256 + threadIdx.x;  // exactly 3072*1024
    int n = i >> 10, k = i & 1023;
    float acc = w1[i];
#pragma unroll
    for (int r = 0; r < 8; r++) acc += B1[n * 8 + r] * A1[r * 1024 + k];
    w1e[i] = f2b(acc);
  } else {
    int i = (b - 20480) * 256 + threadIdx.x;  // exactly 1024*1024
    int n = i >> 10, k = i & 1023;
    float acc = w2[i];
#pragma unroll
    for (int r = 0; r < 8; r++) acc += B2[n * 8 + r] * A2[r * 1024 + k];
    w2e[i] = f2b(acc);
  }
}

// ---- 128x128 GEMM tile (proven gemm_bt body) -------------------------------
// lds: ldsA = lds[0,4096) u16, ldsB = lds[4096,8192).
template <int MODE>
__device__ __forceinline__ void gemm_tile(int bx, int by,
                                          const u16* __restrict__ A,
                                          const u16* __restrict__ Bt,
                                          const float* __restrict__ bias,
                                          float* __restrict__ outf,
                                          u16* __restrict__ kc,
                                          u16* __restrict__ vblk,
                                          u16* lds) {
  u16* ldsA = lds;
  u16* ldsB = lds + 4096;
  const int K = 1024;
  const int t = threadIdx.x;
  const int lane = t & 63, l15 = lane & 15, quad = lane >> 4, w = t >> 6;
  const int wr = (w >> 1) * 64, wc = (w & 1) * 64;
  const long rowA = (long)by * 128;
  const long rowB = (long)bx * 128;
  const int srow = t >> 2, scol = (t & 3) * 8;

  f32x4 acc[4][4];
#pragma unroll
  for (int i = 0; i < 4; i++)
#pragma unroll
    for (int j = 0; j < 4; j++) { f32x4 z = {0.f, 0.f, 0.f, 0.f}; acc[i][j] = z; }

  const u16* Ab = A + rowA * K;
  const u16* Bb = Bt + rowB * K;
  for (int k0 = 0; k0 < K; k0 += 32) {
    __syncthreads();
    async16(Ab + (long)srow * K + k0 + scol, &ldsA[t * 8]);
    async16(Ab + (long)(srow + 64) * K + k0 + scol, &ldsA[2048 + t * 8]);
    async16(Bb + (long)srow * K + k0 + scol, &ldsB[t * 8]);
    async16(Bb + (long)(srow + 64) * K + k0 + scol, &ldsB[2048 + t * 8]);
    __syncthreads();
    bf16x8 af[4], bfr[4];
#pragma unroll
    for (int g = 0; g < 4; g++) {
      af[g]  = *(const bf16x8*)&ldsA[(wr + g * 16 + l15) * 32 + quad * 8];
      bfr[g] = *(const bf16x8*)&ldsB[(wc + g * 16 + l15) * 32 + quad * 8];
    }
#pragma unroll
    for (int i = 0; i < 4; i++)
#pragma unroll
      for (int j = 0; j < 4; j++)
        acc[i][j] = MFMA16(af[i], bfr[j], acc[i][j], 0, 0, 0);
  }

#pragma unroll
  for (int i = 0; i < 4; i++) {
#pragma unroll
    for (int j = 0; j < 4; j++) {
      int n = (int)rowB + wc + j * 16 + l15;
      float bv = bias[n];
#pragma unroll
      for (int r = 0; r < 4; r++) {
        int m = (int)rowA + wr + i * 16 + quad * 4 + r;  // C/D: row=quad*4+reg, col=l15
        float val = acc[i][j][r] + bv;
        if constexpr (MODE == 1) {
          outf[(long)m * C_DIM + n] = val;
        } else {
          int sec = n >> 10;  // 0=q,1=k,2=v (tile-uniform)
          int nc = n & 1023;
          int h = nc >> 6, dd = nc & 63;
          int bb = m >> 11, tt = m & 2047;
          int bh = bb * NHEAD + h;
          if (sec == 0) {
            outf[QOFF + (long)m * C_DIM + nc] = val;
          } else if (sec == 1) {
            outf[KOFF + (long)m * C_DIM + nc] = val;
            kc[(long)bh * (T_LEN * 64) + (long)tt * 64 + dd] = f2b(val);
          } else {
            vblk[(long)bh * (T_LEN * 64) + (long)(tt >> 6) * 4096 + dd * 64 + (tt & 63)] = f2b(val);
          }
        }
      }
    }
  }
}

// ---- paired flash block (R8 body; plds now stride-64 + chunk-XOR swizzle
// so total LDS = 32768 B exactly -> 2 blocks/CU admissible even under 64KB/CU
// cooperative accounting. P[row][col] stored at chunk (col>>3)^(row&7),
// read back with the same XOR -- identical scheme as ldsK/ldsV, same
// conflict class as the old +8 padding.) ------------------------------------
// lds: ldsK = lds[0,4096), ldsV = lds[4096,8192), plds = lds[8192,16384)
// (per-wave stride 2048 u16 = 32 rows x 64).
__device__ __forceinline__ void flash_block_paired(int bid, const float* __restrict__ qsec,
                                                   const u16* __restrict__ kc,
                                                   const u16* __restrict__ vblk,
                                                   u16* __restrict__ yb, u16* lds) {
  u16* ldsK = lds;
  u16* ldsV = lds + 4096;
  const int t = threadIdx.x;
  const int lane = t & 63, l15 = lane & 15, quad = lane >> 4, w = t >> 6;
  u16* pldsw = lds + 8192 + w * 2048;
  const int p = bid >> 6;           // 0..7
  const int bh = bid & 63;
  const int bb = bh >> 4, h = bh & 15;

  bf16x8 ones;
#pragma unroll
  for (int j = 0; j < 8; j++) ones[j] = (short)0x3F80;  // bf16 1.0

  const u16* kcb = kc + (long)bh * (T_LEN * 64);
  const u16* vbb = vblk + (long)bh * (T_LEN * 64);
  // staging source chunk offsets (swizzle: LDS[row][ch] = src[row][ch^(row&7)])
  const int l0 = t, l1 = 256 + t;
  const int s0c = ((l0 >> 3) * 8 + ((l0 & 7) ^ ((l0 >> 3) & 7))) * 8;
  const int s1c = ((l1 >> 3) * 8 + ((l1 & 7) ^ ((l1 >> 3) & 7))) * 8;

#pragma unroll 1
  for (int half = 0; half < 2; half++) {
    const int qt = half ? p : (15 - p);  // heavy tile first
    const int q0 = qt * 128;

    // Q A-frags, pre-scaled by 0.125*log2e (softmax uses exp2)
    const float* Qb = qsec + ((long)bb * T_LEN + q0 + w * 32) * C_DIM + h * DHEAD;
    bf16x8 qf[2][2];
#pragma unroll
    for (int rg = 0; rg < 2; rg++)
#pragma unroll
      for (int kk = 0; kk < 2; kk++) {
        const float* ptr = Qb + (long)(rg * 16 + l15) * C_DIM + kk * 32 + quad * 8;
        f32x4 a = *(const f32x4*)ptr, b = *(const f32x4*)(ptr + 4);
        bf16x8 r;
        r[0] = (short)f2b(a[0] * SCALE_LOG2); r[1] = (short)f2b(a[1] * SCALE_LOG2);
        r[2] = (short)f2b(a[2] * SCALE_LOG2); r[3] = (short)f2b(a[3] * SCALE_LOG2);
        r[4] = (short)f2b(b[0] * SCALE_LOG2); r[5] = (short)f2b(b[1] * SCALE_LOG2);
        r[6] = (short)f2b(b[2] * SCALE_LOG2); r[7] = (short)f2b(b[3] * SCALE_LOG2);
        qf[rg][kk] = r;
      }

    f32x4 o[2][4];
    f32x4 ls[2];  // row-sum accumulator (all cols identical)
#pragma unroll
    for (int rg = 0; rg < 2; rg++) {
#pragma unroll
      for (int cg = 0; cg < 4; cg++) { f32x4 z = {0.f, 0.f, 0.f, 0.f}; o[rg][cg] = z; }
      f32x4 z = {0.f, 0.f, 0.f, 0.f}; ls[rg] = z;
    }

    const int qminw = q0 + w * 32;
    const int nkt = (q0 + 128) >> 6;
    for (int kt = 0; kt < nkt; kt++) {
      const int kb0 = kt * 64;
      __syncthreads();  // all reads of previous tile done (covers cross-half too)
      {
        const u16* ks = kcb + (long)kb0 * 64;
        const u16* vs = vbb + (long)kt * 4096;
        async16(ks + s0c, &ldsK[l0 * 8]);
        async16(ks + s1c, &ldsK[l1 * 8]);
        async16(vs + s0c, &ldsV[l0 * 8]);
        async16(vs + s1c, &ldsV[l1 * 8]);
      }
      __syncthreads();  // staging drained (compiler emits vmcnt(0) before barrier)
      if (kb0 > qminw + 31) continue;  // tile fully above diagonal for this wave

      // S = Q K^T (scaled): s[rg][kg], cols kg*16+l15, rows qminw+rg*16+quad*4+r
      f32x4 s[2][4];
#pragma unroll
      for (int rg = 0; rg < 2; rg++)
#pragma unroll
        for (int kg = 0; kg < 4; kg++) { f32x4 z = {0.f, 0.f, 0.f, 0.f}; s[rg][kg] = z; }
#pragma unroll
      for (int kg = 0; kg < 4; kg++) {
        int row = kg * 16 + l15, sw = row & 7;
        bf16x8 kf0 = *(const bf16x8*)&ldsK[row * 64 + ((quad ^ sw) * 8)];
        bf16x8 kf1 = *(const bf16x8*)&ldsK[row * 64 + (((4 + quad) ^ sw) * 8)];
#pragma unroll
        for (int rg = 0; rg < 2; rg++) {
          s[rg][kg] = MFMA16(qf[rg][0], kf0, s[rg][kg], 0, 0, 0);
          s[rg][kg] = MFMA16(qf[rg][1], kf1, s[rg][kg], 0, 0, 0);
        }
      }
      const bool needMask = (kb0 + 63) > qminw;  // wave-uniform
#pragma unroll
      for (int rg = 0; rg < 2; rg++) {
#pragma unroll
        for (int r = 0; r < 4; r++) {
          float v0 = s[rg][0][r], v1 = s[rg][1][r], v2 = s[rg][2][r], v3 = s[rg][3][r];
          if (needMask) {
            int qrow = qminw + rg * 16 + quad * 4 + r;
            if (kb0 + l15 > qrow)      v0 = -3.0e38f;
            if (kb0 + 16 + l15 > qrow) v1 = -3.0e38f;
            if (kb0 + 32 + l15 > qrow) v2 = -3.0e38f;
            if (kb0 + 48 + l15 > qrow) v3 = -3.0e38f;
          }
          // fixed-base: p = exp2(s); exp2(-3e38)=0 handles the mask.
          // P[prow][col] -> chunk (col>>3)^(prow&7), byte offset col&7
          int prow = rg * 16 + quad * 4 + r;
          int sw8 = prow & 7;
          int cb = l15 >> 3;
          int rb = prow * 64 + (l15 & 7);
          pldsw[rb + ((((0 + cb) ^ sw8)) << 3)] = f2b_tr(exp2f(v0));
          pldsw[rb + ((((2 + cb) ^ sw8)) << 3)] = f2b_tr(exp2f(v1));
          pldsw[rb + ((((4 + cb) ^ sw8)) << 3)] = f2b_tr(exp2f(v2));
          pldsw[rb + ((((6 + cb) ^ sw8)) << 3)] = f2b_tr(exp2f(v3));
        }
      }
      asm volatile("s_waitcnt lgkmcnt(0)" ::: "memory");  // wave-local P visible
      bf16x8 pf[2][2];
#pragma unroll
      for (int rg = 0; rg < 2; rg++)
#pragma unroll
        for (int kk = 0; kk < 2; kk++)
          pf[rg][kk] = *(const bf16x8*)&pldsw[(rg * 16 + l15) * 64 +
                                             (((kk * 4 + quad) ^ (l15 & 7)) << 3)];
      // l-accumulate via ones-column MFMA (rows match o's C-layout rows)
#pragma unroll
      for (int rg = 0; rg < 2; rg++) {
        ls[rg] = MFMA16(pf[rg][0], ones, ls[rg], 0, 0, 0);
        ls[rg] = MFMA16(pf[rg][1], ones, ls[rg], 0, 0, 0);
      }
#pragma unroll
      for (int cg = 0; cg < 4; cg++) {
        int row = cg * 16 + l15, sw = row & 7;
        bf16x8 vf0 = *(const bf16x8*)&ldsV[row * 64 + ((quad ^ sw) * 8)];
        bf16x8 vf1 = *(const bf16x8*)&ldsV[row * 64 + (((4 + quad) ^ sw) * 8)];
#pragma unroll
        for (int rg = 0; rg < 2; rg++) {
          o[rg][cg] = MFMA16(pf[rg][0], vf0, o[rg][cg], 0, 0, 0);
          o[rg][cg] = MFMA16(pf[rg][1], vf1, o[rg][cg], 0, 0, 0);
        }
      }
    }

    // epilogue -> yb bf16 [b*T + t][C]
#pragma unroll
    for (int rg = 0; rg < 2; rg++) {
#pragma unroll
      for (int r = 0; r < 4; r++) {
        float inv = 1.0f / ls[rg][r];
        int tt = q0 + w * 32 + rg * 16 + quad * 4 + r;
        long base = ((long)bb * T_LEN + tt) * C_DIM + h * DHEAD;
#pragma unroll
        for (int cg = 0; cg < 4; cg++)
          yb[base + cg * 16 + l15] = f2b(o[rg][cg][r] * inv);
      }
    }
  }
}

// ---- standalone fallback kernels (proven 4-launch R8 path) -----------------
__global__ __launch_bounds__(256) void prep_all(const float* __restrict__ x,
                                                u16* __restrict__ xc,
                                                const float* __restrict__ w1,
                                                const float* __restrict__ B1,
                                                const float* __restrict__ A1,
                                                u16* __restrict__ w1e,
                                                const float* __restrict__ w2,
                                                const float* __restrict__ B2,
                                                const float* __restrict__ A2,
                                                u16* __restrict__ w2e) {
  prep_unit(blockIdx.x, x, xc, w1, B1, A1, w1e, w2, B2, A2, w2e);
}

template <int MODE>
__global__ __launch_bounds__(256) void gemm_bt(const u16* __restrict__ A,
                                               const u16* __restrict__ Bt,
                                               const float* __restrict__ bias,
                                               float* __restrict__ outf,
                                               u16* __restrict__ kc,
                                               u16* __restrict__ vblk) {
  __shared__ __align__(16) u16 lds[8192];
  gemm_tile<MODE>(blockIdx.x, blockIdx.y, A, Bt, bias, outf, kc, vblk, lds);
}

__global__ __launch_bounds__(256) void flash_attn(const float* __restrict__ qsec,
                                                  const u16* __restrict__ kc,
                                                  const u16* __restrict__ vblk,
                                                  u16* __restrict__ yb) {
  __shared__ __align__(16) u16 lds[16384];
  flash_block_paired(blockIdx.x, qsec, kc, vblk, yb, lds);
}

// ---- fused persistent kernel (R8 diagnosis: ~30-100 us of the 357 total is
// inter-dispatch overhead / boundary cache flushes). 512 blocks x 256 thr,
// 2 blocks/CU co-resident (LDS 32768 B x 2 = 65536 <= per-CU budget; VGPR
// <=256 via launch_bounds(256,2)); phases split by grid.sync(). Work maps
// (all uniform, no atomics):
//   P0 prep: grid-stride 48 units/block.
//   P1 gemm1 (1536 tiles): tiles bid, bid+512, bid+1024.
//   P2 flash: paired (2 q-tiles/block, R8 structure).
//   P3 gemm2 (512 tiles): tile bid.
// __threadfence() (agent fence) before each sync for cross-XCD visibility.
__global__ __launch_bounds__(256, 2) void fused_all(
    const float* __restrict__ x,
    const float* __restrict__ w1, const float* __restrict__ b1,
    const float* __restrict__ A1, const float* __restrict__ B1,
    const float* __restrict__ w2, const float* __restrict__ b2,
    const float* __restrict__ A2, const float* __restrict__ B2,
    float* __restrict__ outf, u16* __restrict__ xc, u16* __restrict__ w1e,
    u16* __restrict__ w2e, u16* __restrict__ yb, u16* __restrict__ kc,
    u16* __restrict__ vblk) {
  cg::grid_group grid = cg::this_grid();
  __shared__ __align__(16) u16 lds[16384];  // 32768 B
  const int bid = blockIdx.x;

  // P0: prep
  for (int u = bid; u < 24576; u += 512)
    prep_unit(u, x, xc, w1, B1, A1, w1e, w2, B2, A2, w2e);
  __threadfence();
  grid.sync();

  // P1: QKV GEMM, 3 uniform tiles/block
#pragma unroll 1
  for (int rpt = 0; rpt < 3; rpt++) {
    int idx = bid + rpt * 512;
    gemm_tile<0>(idx % 24, idx / 24, xc, w1e, b1, outf, kc, vblk, lds);
  }
  __threadfence();
  grid.sync();

  // P2: flash attention (paired)
  flash_block_paired(bid, outf + QOFF, kc, vblk, yb, lds);
  __threadfence();
  grid.sync();

  // P3: projection GEMM, 1 tile/block
  gemm_tile<1>(bid & 7, bid >> 3, yb, w2e, b2, outf, nullptr, nullptr, lds);
}

extern "C" void kernel_launch(void* const* d_in, const int* in_sizes, int n_in,
                              void* d_out, int out_size, void* d_ws, size_t ws_size,
                              hipStream_t stream) {
  const float* x  = (const float*)d_in[0];
  const float* w1 = (const float*)d_in[1];
  const float* b1 = (const float*)d_in[2];
  const float* A1 = (const float*)d_in[3];
  const float* B1 = (const float*)d_in[4];
  const float* w2 = (const float*)d_in[5];
  const float* b2 = (const float*)d_in[6];
  const float* A2 = (const float*)d_in[7];
  const float* B2 = (const float*)d_in[8];
  float* outf = (float*)d_out;
  u16* outb16 = (u16*)d_out;

  // ws (u16 elems), max footprint 25.2 MB (unchanged layout):
  u16* ws  = (u16*)d_ws;
  u16* w2e = ws;                  // [0, 1M)      bf16 W2_eff (alive thru P3)
  u16* w1e = ws + 1048576;        // [1M, 4M)     bf16 W1_eff (dead after P1)
  u16* xc  = ws + 4194304;        // [4M, 12.58M) bf16 x (dead after P1)
  u16* yb  = ws + 1048576;        // aliases w1e/xc head; written in P2
  // d_out out-section (fp32 bytes [0,32M)) used as bf16 scratch until P3:
  u16* vblk = outb16;             // bytes [0,16M): V tile-blocked [bh][kt][dd][tk]
  u16* kcp  = outb16 + 8388608;   // bytes [16M,32M): K packed [bh][t][64]

  // One-time admissibility check (host-side only; capture-safe):
  // cooperative launch supported AND fused_all co-residency >= 2 blocks/CU.
  static int coop_ok = -1;
  if (coop_ok < 0) {
    int dev = 0;
    hipGetDevice(&dev);
    int attr = 0;
    hipDeviceGetAttribute(&attr, hipDeviceAttributeCooperativeLaunch, dev);
    int nb = 0;
    hipOccupancyMaxActiveBlocksPerMultiprocessor(&nb, (const void*)fused_all, 256, 0);
    coop_ok = (attr != 0 && nb >= 2) ? 1 : 0;
  }

  if (coop_ok == 1) {
    void* args[] = {
      (void*)&x, (void*)&w1, (void*)&b1, (void*)&A1, (void*)&B1,
      (void*)&w2, (void*)&b2, (void*)&A2, (void*)&B2,
      (void*)&outf, (void*)&xc, (void*)&w1e, (void*)&w2e, (void*)&yb,
      (void*)&kcp, (void*)&vblk
    };
    hipError_t e = hipLaunchCooperativeKernel((const void*)fused_all, dim3(512),
                                              dim3(256), args, 0, stream);
    if (e == hipSuccess) return;
    coop_ok = 0;  // refused at launch -> permanent fallback
  }

  // Fallback: proven 4-launch path (R8-equivalent, ~357 us)
  prep_all<<<24576, 256, 0, stream>>>(x, xc, w1, B1, A1, w1e, w2, B2, A2, w2e);
  gemm_bt<0><<<dim3(24, 64), 256, 0, stream>>>(xc, w1e, b1, outf, kcp, vblk);
  flash_attn<<<512, 256, 0, stream>>>(outf + QOFF, kcp, vblk, yb);
  gemm_bt<1><<<dim3(8, 64), 256, 0, stream>>>(yb, w2e, b2, outf, nullptr, nullptr);
}

// Round 11
// 338.604 us; speedup vs baseline: 1.0552x; 1.0552x over previous
//
#include <hip/hip_runtime.h>
#include <stdint.h>

// Problem constants: B=4, T=2048, C=1024, H=16, d=64, R=8. Inputs/outputs fp32.
#define T_LEN 2048
#define C_DIM 1024
#define NHEAD 16
#define DHEAD 64
#define QOFF  8388608L   // float-elem offset of q section in d_out
#define KOFF  16777216L  // float-elem offset of k section in d_out
#define SCALE_LOG2 0.18033688011112042f  // 0.125 * log2(e)

typedef float f32x4 __attribute__((ext_vector_type(4)));
typedef short bf16x8 __attribute__((ext_vector_type(8)));
typedef short s16x4 __attribute__((ext_vector_type(4)));
typedef unsigned short u16;

__device__ __forceinline__ u16 f2b(float f) {
  union { float f; uint32_t u; } v; v.f = f;
  uint32_t r = v.u + 0x7fffu + ((v.u >> 16) & 1u);  // RNE
  return (u16)(r >> 16);
}
__device__ __forceinline__ u16 f2b_tr(float f) {  // truncation: 1 VALU op
  union { float f; uint32_t u; } v; v.f = f;
  return (u16)(v.u >> 16);
}
__device__ __forceinline__ void async16(const u16* g, u16* l) {
  __builtin_amdgcn_global_load_lds((const __attribute__((address_space(1))) void*)g,
                                   (__attribute__((address_space(3))) void*)l, 16, 0, 0);
}

#define MFMA16 __builtin_amdgcn_mfma_f32_16x16x32_bf16

// Fused prep (proven R6). Blocks [0,8192): x fp32 -> bf16.
// [8192,20480): W1_eff. [20480,24576): W2_eff. Disjoint I/O, one dispatch.
__global__ __launch_bounds__(256) void prep_all(const float* __restrict__ x,
                                                u16* __restrict__ xc,
                                                const float* __restrict__ w1,
                                                const float* __restrict__ B1,
                                                const float* __restrict__ A1,
                                                u16* __restrict__ w1e,
                                                const float* __restrict__ w2,
                                                const float* __restrict__ B2,
                                                const float* __restrict__ A2,
                                                u16* __restrict__ w2e) {
  int b = blockIdx.x;
  if (b < 8192) {
    long i = ((long)b * 256 + threadIdx.x) * 4;
    f32x4 v = *(const f32x4*)(x + i);
    s16x4 r;
    r[0] = (short)f2b(v[0]); r[1] = (short)f2b(v[1]);
    r[2] = (short)f2b(v[2]); r[3] = (short)f2b(v[3]);
    *(s16x4*)(xc + i) = r;
  } else if (b < 20480) {
    int i = (b - 8192) * 256 + threadIdx.x;  // exactly 3072*1024
    int n = i >> 10, k = i & 1023;
    float acc = w1[i];
#pragma unroll
    for (int r = 0; r < 8; r++) acc += B1[n * 8 + r] * A1[r * 1024 + k];
    w1e[i] = f2b(acc);
  } else {
    int i = (b - 20480) * 256 + threadIdx.x;  // exactly 1024*1024
    int n = i >> 10, k = i & 1023;
    float acc = w2[i];
#pragma unroll
    for (int r = 0; r < 8; r++) acc += B2[n * 8 + r] * A2[r * 1024 + k];
    w2e[i] = f2b(acc);
  }
}

// C[M,N] = A[M,K]*Bt[N,K]^T + bias. A bf16, bias fp32, out fp32. 128x128 tile, BK=32.
// Proven R0 kernel (108-110 us MODE 0, single launch).
// MODE 0: q/k -> d_out fp32 sections; k also -> kc bf16 [bh][t][64];
//         v -> vblk bf16 [bh][t>>6][dd][t&63]. MODE 1: -> d_out[0,M*C) fp32.
template <int MODE>
__global__ __launch_bounds__(256) void gemm_bt(const u16* __restrict__ A,
                                               const u16* __restrict__ Bt,
                                               const float* __restrict__ bias,
                                               float* __restrict__ outf,
                                               u16* __restrict__ kc,
                                               u16* __restrict__ vblk, int K) {
  __shared__ __align__(16) u16 ldsA[128 * 32];
  __shared__ __align__(16) u16 ldsB[128 * 32];
  const int t = threadIdx.x;
  const int lane = t & 63, l15 = lane & 15, quad = lane >> 4, w = t >> 6;
  const int wr = (w >> 1) * 64, wc = (w & 1) * 64;
  const long rowA = (long)blockIdx.y * 128;
  const long rowB = (long)blockIdx.x * 128;
  const int srow = t >> 2, scol = (t & 3) * 8;

  f32x4 acc[4][4];
#pragma unroll
  for (int i = 0; i < 4; i++)
#pragma unroll
    for (int j = 0; j < 4; j++) { f32x4 z = {0.f, 0.f, 0.f, 0.f}; acc[i][j] = z; }

  const u16* Ab = A + rowA * K;
  const u16* Bb = Bt + rowB * K;
  for (int k0 = 0; k0 < K; k0 += 32) {
    __syncthreads();
    async16(Ab + (long)srow * K + k0 + scol, &ldsA[t * 8]);
    async16(Ab + (long)(srow + 64) * K + k0 + scol, &ldsA[2048 + t * 8]);
    async16(Bb + (long)srow * K + k0 + scol, &ldsB[t * 8]);
    async16(Bb + (long)(srow + 64) * K + k0 + scol, &ldsB[2048 + t * 8]);
    __syncthreads();
    bf16x8 af[4], bfr[4];
#pragma unroll
    for (int g = 0; g < 4; g++) {
      af[g]  = *(const bf16x8*)&ldsA[(wr + g * 16 + l15) * 32 + quad * 8];
      bfr[g] = *(const bf16x8*)&ldsB[(wc + g * 16 + l15) * 32 + quad * 8];
    }
#pragma unroll
    for (int i = 0; i < 4; i++)
#pragma unroll
      for (int j = 0; j < 4; j++)
        acc[i][j] = MFMA16(af[i], bfr[j], acc[i][j], 0, 0, 0);
  }

#pragma unroll
  for (int i = 0; i < 4; i++) {
#pragma unroll
    for (int j = 0; j < 4; j++) {
      int n = (int)rowB + wc + j * 16 + l15;
      float bv = bias[n];
#pragma unroll
      for (int r = 0; r < 4; r++) {
        int m = (int)rowA + wr + i * 16 + quad * 4 + r;  // C/D: row=quad*4+reg, col=l15
        float val = acc[i][j][r] + bv;
        if constexpr (MODE == 1) {
          outf[(long)m * C_DIM + n] = val;
        } else {
          int sec = n >> 10;  // 0=q,1=k,2=v (block-uniform)
          int nc = n & 1023;
          int h = nc >> 6, dd = nc & 63;
          int bb = m >> 11, tt = m & 2047;
          int bh = bb * NHEAD + h;
          if (sec == 0) {
            outf[QOFF + (long)m * C_DIM + nc] = val;
          } else if (sec == 1) {
            outf[KOFF + (long)m * C_DIM + nc] = val;
            kc[(long)bh * (T_LEN * 64) + (long)tt * 64 + dd] = f2b(val);
          } else {
            vblk[(long)bh * (T_LEN * 64) + (long)(tt >> 6) * 4096 + dd * 64 + (tt & 63)] = f2b(val);
          }
        }
      }
    }
  }
}

// Flash attention: R5's directly-measured 79-us body, UNCHANGED.
// (R10 cross-round A/B: LPT-1024 at 4 blocks/CU beats paired-512 at
// 2 blocks/CU by ~25 us -- TLP beats uniformity; R3(6 launches, LPT)=350.6
// < R8(4 launches, paired)=357.1. This round pairs the LPT flash with the
// 4-launch structure for the first time.)
// Single-buffered LDS K/V staging (de-duplicates K/V across the 4 waves;
// direct-global was 2x worse), fixed-base softmax (m=0; scores bounded ~|15|),
// row-sum l via ones-column MFMA, XOR chunk swizzle on staging.
__global__ __launch_bounds__(256) void flash_attn(const float* __restrict__ qsec,
                                                  const u16* __restrict__ kc,
                                                  const u16* __restrict__ vblk,
                                                  u16* __restrict__ yb) {
  __shared__ __align__(16) u16 ldsK[64 * 64];
  __shared__ __align__(16) u16 ldsV[64 * 64];
  __shared__ __align__(16) u16 plds[4][32 * 72];  // per-wave P, stride 72 (16B-aligned)
  const int t = threadIdx.x;
  const int lane = t & 63, l15 = lane & 15, quad = lane >> 4, w = t >> 6;
  const int qt = 15 - (blockIdx.x >> 6);   // heavy q-tiles dispatch first (LPT)
  const int bh = blockIdx.x & 63;
  const int q0 = qt * 128;
  const int bb = bh >> 4, h = bh & 15;

  // Q A-frags, pre-scaled by 0.125*log2e (softmax uses exp2)
  const float* Qb = qsec + ((long)bb * T_LEN + q0 + w * 32) * C_DIM + h * DHEAD;
  bf16x8 qf[2][2];
#pragma unroll
  for (int rg = 0; rg < 2; rg++)
#pragma unroll
    for (int kk = 0; kk < 2; kk++) {
      const float* p = Qb + (long)(rg * 16 + l15) * C_DIM + kk * 32 + quad * 8;
      f32x4 a = *(const f32x4*)p, b = *(const f32x4*)(p + 4);
      bf16x8 r;
      r[0] = (short)f2b(a[0] * SCALE_LOG2); r[1] = (short)f2b(a[1] * SCALE_LOG2);
      r[2] = (short)f2b(a[2] * SCALE_LOG2); r[3] = (short)f2b(a[3] * SCALE_LOG2);
      r[4] = (short)f2b(b[0] * SCALE_LOG2); r[5] = (short)f2b(b[1] * SCALE_LOG2);
      r[6] = (short)f2b(b[2] * SCALE_LOG2); r[7] = (short)f2b(b[3] * SCALE_LOG2);
      qf[rg][kk] = r;
    }

  bf16x8 ones;
#pragma unroll
  for (int j = 0; j < 8; j++) ones[j] = (short)0x3F80;  // bf16 1.0

  f32x4 o[2][4];
  f32x4 ls[2];  // row-sum accumulator (all cols identical)
#pragma unroll
  for (int rg = 0; rg < 2; rg++) {
#pragma unroll
    for (int cg = 0; cg < 4; cg++) { f32x4 z = {0.f, 0.f, 0.f, 0.f}; o[rg][cg] = z; }
    f32x4 z = {0.f, 0.f, 0.f, 0.f}; ls[rg] = z;
  }

  const u16* kcb = kc + (long)bh * (T_LEN * 64);
  const u16* vbb = vblk + (long)bh * (T_LEN * 64);
  // staging source chunk offsets (swizzle: LDS[row][ch] = src[row][ch^(row&7)])
  const int l0 = t, l1 = 256 + t;
  const int s0c = ((l0 >> 3) * 8 + ((l0 & 7) ^ ((l0 >> 3) & 7))) * 8;
  const int s1c = ((l1 >> 3) * 8 + ((l1 & 7) ^ ((l1 >> 3) & 7))) * 8;

  const int qminw = q0 + w * 32;
  const int nkt = (q0 + 128) >> 6;
  for (int kt = 0; kt < nkt; kt++) {
    const int kb0 = kt * 64;
    __syncthreads();  // all reads of previous tile done
    {
      const u16* ks = kcb + (long)kb0 * 64;
      const u16* vs = vbb + (long)kt * 4096;
      async16(ks + s0c, &ldsK[l0 * 8]);
      async16(ks + s1c, &ldsK[l1 * 8]);
      async16(vs + s0c, &ldsV[l0 * 8]);
      async16(vs + s1c, &ldsV[l1 * 8]);
    }
    __syncthreads();  // staging drained (compiler emits vmcnt(0) before barrier)
    if (kb0 > qminw + 31) continue;  // tile fully above diagonal for this wave

    // S = Q K^T (scaled): s[rg][kg], cols kg*16+l15, rows qminw+rg*16+quad*4+r
    f32x4 s[2][4];
#pragma unroll
    for (int rg = 0; rg < 2; rg++)
#pragma unroll
      for (int kg = 0; kg < 4; kg++) { f32x4 z = {0.f, 0.f, 0.f, 0.f}; s[rg][kg] = z; }
#pragma unroll
    for (int kg = 0; kg < 4; kg++) {
      int row = kg * 16 + l15, sw = row & 7;
      bf16x8 kf0 = *(const bf16x8*)&ldsK[row * 64 + ((quad ^ sw) * 8)];
      bf16x8 kf1 = *(const bf16x8*)&ldsK[row * 64 + (((4 + quad) ^ sw) * 8)];
#pragma unroll
      for (int rg = 0; rg < 2; rg++) {
        s[rg][kg] = MFMA16(qf[rg][0], kf0, s[rg][kg], 0, 0, 0);
        s[rg][kg] = MFMA16(qf[rg][1], kf1, s[rg][kg], 0, 0, 0);
      }
    }
    const bool needMask = (kb0 + 63) > qminw;  // wave-uniform
#pragma unroll
    for (int rg = 0; rg < 2; rg++) {
#pragma unroll
      for (int r = 0; r < 4; r++) {
        float v0 = s[rg][0][r], v1 = s[rg][1][r], v2 = s[rg][2][r], v3 = s[rg][3][r];
        if (needMask) {
          int qrow = qminw + rg * 16 + quad * 4 + r;
          if (kb0 + l15 > qrow)      v0 = -3.0e38f;
          if (kb0 + 16 + l15 > qrow) v1 = -3.0e38f;
          if (kb0 + 32 + l15 > qrow) v2 = -3.0e38f;
          if (kb0 + 48 + l15 > qrow) v3 = -3.0e38f;
        }
        // fixed-base: p = exp2(s); exp2(-3e38)=0 handles the mask
        int prow = rg * 16 + quad * 4 + r;
        plds[w][prow * 72 + l15]      = f2b_tr(exp2f(v0));
        plds[w][prow * 72 + 16 + l15] = f2b_tr(exp2f(v1));
        plds[w][prow * 72 + 32 + l15] = f2b_tr(exp2f(v2));
        plds[w][prow * 72 + 48 + l15] = f2b_tr(exp2f(v3));
      }
    }
    asm volatile("s_waitcnt lgkmcnt(0)" ::: "memory");  // wave-local P visible
    bf16x8 pf[2][2];
#pragma unroll
    for (int rg = 0; rg < 2; rg++)
#pragma unroll
      for (int kk = 0; kk < 2; kk++)
        pf[rg][kk] = *(const bf16x8*)&plds[w][(rg * 16 + l15) * 72 + kk * 32 + quad * 8];
    // l-accumulate via ones-column MFMA (rows match o's C-layout rows)
#pragma unroll
    for (int rg = 0; rg < 2; rg++) {
      ls[rg] = MFMA16(pf[rg][0], ones, ls[rg], 0, 0, 0);
      ls[rg] = MFMA16(pf[rg][1], ones, ls[rg], 0, 0, 0);
    }
#pragma unroll
    for (int cg = 0; cg < 4; cg++) {
      int row = cg * 16 + l15, sw = row & 7;
      bf16x8 vf0 = *(const bf16x8*)&ldsV[row * 64 + ((quad ^ sw) * 8)];
      bf16x8 vf1 = *(const bf16x8*)&ldsV[row * 64 + (((4 + quad) ^ sw) * 8)];
#pragma unroll
      for (int rg = 0; rg < 2; rg++) {
        o[rg][cg] = MFMA16(pf[rg][0], vf0, o[rg][cg], 0, 0, 0);
        o[rg][cg] = MFMA16(pf[rg][1], vf1, o[rg][cg], 0, 0, 0);
      }
    }
  }
  // epilogue -> yb bf16 [b*T + t][C]
#pragma unroll
  for (int rg = 0; rg < 2; rg++) {
#pragma unroll
    for (int r = 0; r < 4; r++) {
      float inv = 1.0f / ls[rg][r];
      int tt = q0 + w * 32 + rg * 16 + quad * 4 + r;
      long base = ((long)bb * T_LEN + tt) * C_DIM + h * DHEAD;
#pragma unroll
      for (int cg = 0; cg < 4; cg++)
        yb[base + cg * 16 + l15] = f2b(o[rg][cg][r] * inv);
    }
  }
}

extern "C" void kernel_launch(void* const* d_in, const int* in_sizes, int n_in,
                              void* d_out, int out_size, void* d_ws, size_t ws_size,
                              hipStream_t stream) {
  const float* x  = (const float*)d_in[0];
  const float* w1 = (const float*)d_in[1];
  const float* b1 = (const float*)d_in[2];
  const float* A1 = (const float*)d_in[3];
  const float* B1 = (const float*)d_in[4];
  const float* w2 = (const float*)d_in[5];
  const float* b2 = (const float*)d_in[6];
  const float* A2 = (const float*)d_in[7];
  const float* B2 = (const float*)d_in[8];
  float* outf = (float*)d_out;
  u16* outb16 = (u16*)d_out;

  // ws (u16 elems), max footprint 25.2 MB:
  u16* ws  = (u16*)d_ws;
  u16* w2e = ws;                  // [0, 1M)      bf16 W2_eff
  u16* w1e = ws + 1048576;        // [1M, 4M)     bf16 W1_eff (dead after gemm1)
  u16* xc  = ws + 4194304;        // [4M, 12.5M)  bf16 x (dead after gemm1)
  u16* yb  = ws + 1048576;        // aliases w1e/xc head; written post-gemm1
  // d_out out-section (fp32 bytes [0,32M)) used as bf16 scratch until gemm2:
  u16* vblk = outb16;             // bytes [0,16M): V tile-blocked [bh][kt][dd][tk]
  u16* kcp  = outb16 + 8388608;   // bytes [16M,32M): K packed [bh][t][64]

  prep_all<<<24576, 256, 0, stream>>>(x, xc, w1, B1, A1, w1e, w2, B2, A2, w2e);
  gemm_bt<0><<<dim3(24, 64), 256, 0, stream>>>(xc, w1e, b1, outf, kcp, vblk, 1024);
  flash_attn<<<1024, 256, 0, stream>>>(outf + QOFF, kcp, vblk, yb);
  gemm_bt<1><<<dim3(8, 64), 256, 0, stream>>>(yb, w2e, b2, outf, nullptr, nullptr, 1024);
}